// Round 5
// baseline (12443.016 us; speedup 1.0000x reference)
//
#include <hip/hip_runtime.h>
#include <hip/hip_bf16.h>

typedef __hip_bfloat16 bf16;

#define TOK   8192      // B*S
#define SEQ   4096
#define NHD   16        // heads
#define HD    128       // head dim
#define C2    2048      // H*D
#define CHK   64        // chunk size
#define TB    2048      // tokens per stream block
#define NBB   4         // stream blocks (TOK/TB)
#define NCHB  32        // chunks per stream block (TB/CHK)
#define SW    16        // dv slice width in stage2
#define QSCALE 0.08838834764831845f

__device__ __forceinline__ float b2f(bf16 x){ return __bfloat162float(x); }
__device__ __forceinline__ bf16  f2b(float x){ return __float2bfloat16(x); }
// exp with argument clamped to <=0 (no-op in exact math: all args are <=0)
__device__ __forceinline__ float expn(float x){ return __expf(fminf(x, 0.f)); }

// ---------------------------------------------------------------------------
// All scratch lives in device globals (no d_ws dependence).
// ---------------------------------------------------------------------------
__device__ __attribute__((aligned(16))) unsigned short G_qlin[TB*C2];
__device__ __attribute__((aligned(16))) unsigned short G_klin[TB*C2];
__device__ __attribute__((aligned(16))) unsigned short G_vlin[TB*C2];
__device__ __attribute__((aligned(16))) unsigned short G_qb[TB*C2];
__device__ __attribute__((aligned(16))) unsigned short G_kb[TB*C2];
__device__ __attribute__((aligned(16))) unsigned short G_vb[TB*C2];
__device__ __attribute__((aligned(16))) unsigned short G_qg[TB*C2];
__device__ __attribute__((aligned(16))) unsigned short G_gate[TB*C2];
__device__ __attribute__((aligned(16))) unsigned short G_core[TB*C2];
__device__ __attribute__((aligned(16))) unsigned short G_opre[TB*C2];
__device__ __attribute__((aligned(16))) float          G_g[TB*C2];
__device__ __attribute__((aligned(16))) unsigned short G_attn[NHD*NCHB*CHK*CHK];
__device__ __attribute__((aligned(16))) float          G_egl[NHD*NCHB*HD];
__device__ __attribute__((aligned(16))) float          G_beta[TB*NHD];
__device__ __attribute__((aligned(16))) float          G_fa[TB*HD];
__device__ __attribute__((aligned(16))) unsigned short G_ga[TB*HD];
__device__ __attribute__((aligned(16))) float          G_state[2*NHD*HD*HD];
__device__ __attribute__((aligned(16))) unsigned short G_qtail[3*C2];
__device__ __attribute__((aligned(16))) unsigned short G_ktail[3*C2];
__device__ __attribute__((aligned(16))) unsigned short G_vtail[3*C2];

#define P_QLIN  ((bf16*)G_qlin)
#define P_KLIN  ((bf16*)G_klin)
#define P_VLIN  ((bf16*)G_vlin)
#define P_QB    ((bf16*)G_qb)
#define P_KB    ((bf16*)G_kb)
#define P_VB    ((bf16*)G_vb)
#define P_QG    ((bf16*)G_qg)
#define P_GATE  ((bf16*)G_gate)
#define P_CORE  ((bf16*)G_core)
#define P_OPRE  ((bf16*)G_opre)
#define P_ATTN  ((bf16*)G_attn)
#define P_QT    ((bf16*)G_qtail)
#define P_KT    ((bf16*)G_ktail)
#define P_VT    ((bf16*)G_vtail)

// GEMM scratch-operand selectors (host cannot take device-global addresses)
__device__ __forceinline__ const void* selA_raw(int s){
  switch(s){ case 0: return G_ga; case 1: return G_opre; case 2: return G_fa; }
  return nullptr;
}
__device__ __forceinline__ void* selC_raw(int s){
  switch(s){
    case 0: return G_qlin; case 1: return G_klin; case 2: return G_vlin;
    case 3: return G_beta; case 4: return G_fa;   case 5: return G_ga;
    case 6: return G_g;    case 7: return G_gate;
  }
  return nullptr;
}

// ---------------------------------------------------------------------------
// Tiled GEMM: C[M,N] = A[M,K] @ B[K,N]. A dtype templated (bf16 scratch or
// f32 input), B ALWAYS f32 (weights from d_in), f32 accum.
// 128x128 tile, BK=16, 256 threads, 8x8/thread.
// aSel/cSel >=0 pick device-global scratch; -1 uses the pointer args.
// ---------------------------------------------------------------------------
template<typename AT, int OUT_BF16, int ACT_SIG>
__global__ void __launch_bounds__(256) gemm_k(
    const AT* __restrict__ Ap, int aSel, const float* __restrict__ Bm,
    const float* __restrict__ bias, void* __restrict__ Cp, int cSel,
    int M, int N, int K)
{
  const AT* A = (aSel < 0) ? Ap : (const AT*)selA_raw(aSel);
  void*     Cv = (cSel < 0) ? Cp : selC_raw(cSel);

  __shared__ float As[128][17];
  __shared__ float Bs[16][129];
  const int tx = threadIdx.x, ty = threadIdx.y;
  const int tid = ty*16 + tx;
  const int bm = blockIdx.y * 128, bn = blockIdx.x * 128;

  float acc[8][8];
  #pragma unroll
  for (int i=0;i<8;i++)
    #pragma unroll
    for (int j=0;j<8;j++) acc[i][j]=0.f;

  for (int k0=0; k0<K; k0+=16) {
    { // A tile 128x16, 8 contiguous elems per thread
      int r = tid >> 1, c = (tid & 1)*8;
      const AT* src = A + (size_t)(bm+r)*K + k0 + c;
      if constexpr (sizeof(AT) == 2) {
        float4 f = *(const float4*)src;
        const bf16* e = (const bf16*)&f;
        #pragma unroll
        for (int u=0;u<8;u++) As[r][c+u] = b2f(e[u]);
      } else {
        float4 f0 = *(const float4*)src;
        float4 f1 = *(const float4*)(src+4);
        As[r][c+0]=f0.x; As[r][c+1]=f0.y; As[r][c+2]=f0.z; As[r][c+3]=f0.w;
        As[r][c+4]=f1.x; As[r][c+5]=f1.y; As[r][c+6]=f1.z; As[r][c+7]=f1.w;
      }
    }
    { // B tile 16x128 (f32)
      int r = tid >> 4, c = (tid & 15)*8;
      int gn = bn + c;
      const float* src = Bm + (size_t)(k0+r)*N + gn;
      if (gn + 7 < N) {
        float4 f0 = *(const float4*)src;
        float4 f1 = *(const float4*)(src+4);
        Bs[r][c+0]=f0.x; Bs[r][c+1]=f0.y; Bs[r][c+2]=f0.z; Bs[r][c+3]=f0.w;
        Bs[r][c+4]=f1.x; Bs[r][c+5]=f1.y; Bs[r][c+6]=f1.z; Bs[r][c+7]=f1.w;
      } else {
        #pragma unroll
        for (int u=0;u<8;u++)
          Bs[r][c+u] = (gn+u < N) ? src[u] : 0.f;
      }
    }
    __syncthreads();
    #pragma unroll
    for (int kk=0;kk<16;kk++){
      float a[8], b[8];
      #pragma unroll
      for (int i=0;i<8;i++) a[i] = As[ty + 16*i][kk];
      #pragma unroll
      for (int j=0;j<8;j++) b[j] = Bs[kk][tx + 16*j];
      #pragma unroll
      for (int i=0;i<8;i++)
        #pragma unroll
        for (int j=0;j<8;j++) acc[i][j] += a[i]*b[j];
    }
    __syncthreads();
  }
  #pragma unroll
  for (int i=0;i<8;i++){
    int m = bm + ty + 16*i;
    #pragma unroll
    for (int j=0;j<8;j++){
      int n = bn + tx + 16*j;
      if (n < N) {
        float v = acc[i][j];
        if (bias) v += bias[n];
        if (ACT_SIG) v = 1.f/(1.f + __expf(-v));
        if (OUT_BF16) ((bf16*)Cv)[(size_t)m*N + n] = f2b(v);
        else          ((float*)Cv)[(size_t)m*N + n] = v;
      }
    }
  }
}

// ---------------------------------------------------------------------------
// Causal depthwise conv (K=4) + SiLU + optional per-head l2norm.
// sel: 0=q 1=k 2=v.  Reads G_{q,k,v}lin + tails, writes G_{q,k,v}b.
// ---------------------------------------------------------------------------
__global__ void __launch_bounds__(256) conv_silu_k(
    int sel, const float* __restrict__ kern, int s0, int do_norm)
{
  const bf16* lin  = sel==0 ? P_QLIN : sel==1 ? P_KLIN : P_VLIN;
  const bf16* tail = sel==0 ? P_QT   : sel==1 ? P_KT   : P_VT;
  bf16*       out  = sel==0 ? P_QB   : sel==1 ? P_KB   : P_VB;

  __shared__ float part[256];
  __shared__ float scal[16];
  const int t = threadIdx.x;
  const int r = blockIdx.x;          // block-local token
  const int s = s0 + r;              // seq position within batch
  const int c0 = t*8;
  float v[8];
  #pragma unroll
  for (int u=0;u<8;u++) v[u]=0.f;
  for (int j=0;j<4;j++){
    int sp = s - 3 + j;
    if (sp < 0) continue;            // causal pad at batch start
    int rl = r - 3 + j;
    const bf16* row = (rl >= 0) ? lin + (size_t)rl*C2 + c0
                                : tail + (size_t)(rl+3)*C2 + c0;
    const float* kr = kern + j*C2 + c0;
    #pragma unroll
    for (int u=0;u<8;u++) v[u] += b2f(row[u]) * kr[u];
  }
  #pragma unroll
  for (int u=0;u<8;u++){ float x=v[u]; v[u] = x / (1.f + __expf(-x)); }
  if (do_norm) {
    float ss=0.f;
    #pragma unroll
    for (int u=0;u<8;u++) ss += v[u]*v[u];
    part[t]=ss; __syncthreads();
    if (t<16){
      float s2=0.f;
      for (int i=0;i<16;i++) s2 += part[t*16+i];
      scal[t] = rsqrtf(s2 + 1e-6f);
    }
    __syncthreads();
    float sc = scal[t>>4];
    #pragma unroll
    for (int u=0;u<8;u++) v[u] *= sc;
  }
  bf16* orow = out + (size_t)r*C2 + c0;
  #pragma unroll
  for (int u=0;u<8;u++) orow[u] = f2b(v[u]);
}

// Save last 3 rows of qlin/klin/vlin for next block's conv.
__global__ void __launch_bounds__(256) tail_save_k()
{
  int i = blockIdx.x*256 + threadIdx.x;   // 3 bufs * 3 rows * 2048
  int buf = i / (3*C2), rem = i % (3*C2);
  const bf16* s = (buf==0?P_QLIN:buf==1?P_KLIN:P_VLIN) + (size_t)(TB-3)*C2 + rem;
  bf16* d = (buf==0?P_QT:buf==1?P_KT:P_VT) + rem;
  *d = *s;
}

// g = -exp(A_log[h]) * softplus(g_lin), in-place f32 on G_g
__global__ void __launch_bounds__(256) g_transform_k(const float* __restrict__ A_log)
{
  size_t i = (size_t)blockIdx.x*256 + threadIdx.x;
  float x = fminf(G_g[i], 80.f);     // sanitize (also maps NaN -> 80)
  int h = (int)((i >> 7) & (NHD-1));
  float a = __expf(A_log[h]);
  float sp = (x > 20.f) ? x : log1pf(__expf(x));
  G_g[i] = -a * sp;
}

// In-place per-chunk cumsum of g along rows. Grid NHD*NCHB x 128 threads.
__global__ void __launch_bounds__(128) gcum_k()
{
  const int blk = blockIdx.x;
  const int ic = blk % NCHB, h = blk / NCHB;
  const int d = threadIdx.x;
  size_t gi = (size_t)(ic*CHK)*C2 + h*HD + d;
  float a = 0.f;
  for (int r=0;r<CHK;r++){ a += G_g[gi]; G_g[gi] = a; gi += C2; }
}

// ---------------------------------------------------------------------------
// Stage 1: per chunk (NHD*NCHB blocks, 256 thr).  LDS ~50KB.
// In-place: u->vb, w->qb, k_tail->kb.  qg/attn/egl to own globals.
// ---------------------------------------------------------------------------
#define TW 33
__global__ void __launch_bounds__(256) stage1_k()
{
  __shared__ float Am[CHK][CHK+1];     // 16.6 KB
  __shared__ float sh[CHK*(HD+2)];     // 33.3 KB (rhs view / 3 tiles)
  __shared__ float bc[CHK];
  __shared__ float gl[HD];

  bf16* qb = P_QB; bf16* kb = P_KB; bf16* vb = P_VB;
  const float* gc = G_g;

  const int blk = blockIdx.x;
  const int ic  = blk % NCHB;
  const int h   = blk / NCHB;
  const int t   = threadIdx.x;
  const size_t base = (size_t)(ic*CHK)*C2 + h*HD;   // + r*C2 + d

  float* tK = sh;
  float* tG = sh + CHK*TW;
  float* tQ = sh + 2*CHK*TW;
  float (*rhs)[HD+2] = (float(*)[HD+2])sh;

  if (t < CHK) bc[t] = G_beta[(ic*CHK + t)*NHD + h];
  if (t < HD)  gl[t] = gc[base + (size_t)(CHK-1)*C2 + t];
  for (int i=t; i<CHK*(CHK+1); i+=256) ((float*)Am)[i] = 0.f;
  __syncthreads();

  // Phase 1: Am[i][j] = bc[i] * sum_d exp(gc_i-gc_j) k_i k_j  (i>j), d-tiled
  for (int dt=0; dt<4; ++dt){
    const int d0 = dt*32;
    for (int i=t; i<CHK*32; i+=256){
      int r=i>>5, dd=i&31;
      size_t gi = base + (size_t)r*C2 + d0 + dd;
      tK[r*TW+dd] = b2f(kb[gi]);
      tG[r*TW+dd] = gc[gi];
    }
    __syncthreads();
    for (int cell=t; cell<CHK*CHK; cell+=256){
      int i=cell>>6, j=cell&63;
      if (i>j){
        float a=0.f;
        for (int dd=0;dd<32;dd++)
          a += expn(tG[i*TW+dd]-tG[j*TW+dd]) * tK[i*TW+dd]*tK[j*TW+dd];
        Am[i][j] += a;
      }
    }
    __syncthreads();
  }
  for (int cell=t; cell<CHK*CHK; cell+=256){
    int i=cell>>6, j=cell&63;
    Am[i][j] = (i>j) ? Am[i][j]*bc[i] : 0.f;
  }
  __syncthreads();

  // Phase 2a: solve (I+A) u = bc*v, write u -> vb in place
  for (int i=t;i<CHK*HD;i+=256){
    int r=i>>7, d=i&127;
    rhs[r][d] = bc[r]*b2f(vb[base + (size_t)r*C2 + d]);
  }
  __syncthreads();
  if (t < HD){
    const int c=t;
    for (int i=1;i<CHK;i++){
      float a = rhs[i][c];
      for (int kk=0;kk<i;kk++) a -= Am[i][kk]*rhs[kk][c];
      rhs[i][c]=a;
    }
  }
  __syncthreads();
  for (int i=t;i<CHK*HD;i+=256){
    int r=i>>7,d=i&127;
    vb[base+(size_t)r*C2+d] = f2b(rhs[r][d]);
  }
  __syncthreads();

  // Phase 3: attn[i][j] = sum_d exp(gc_i-gc_j) (QSCALE q_i) k_j (i>=j), regs
  float areg[16];
  #pragma unroll
  for (int m=0;m<16;m++) areg[m]=0.f;
  for (int dt=0; dt<4; ++dt){
    const int d0=dt*32;
    for (int i=t;i<CHK*32;i+=256){
      int r=i>>5, dd=i&31;
      size_t gi = base + (size_t)r*C2 + d0+dd;
      tK[r*TW+dd]=b2f(kb[gi]);
      tG[r*TW+dd]=gc[gi];
      tQ[r*TW+dd]=QSCALE*b2f(qb[gi]);
    }
    __syncthreads();
    #pragma unroll
    for (int m=0;m<16;m++){
      int cell=t+256*m, i=cell>>6, j=cell&63;
      if (i>=j){
        float a=0.f;
        for (int dd=0;dd<32;dd++)
          a += expn(tG[i*TW+dd]-tG[j*TW+dd]) * tQ[i*TW+dd]*tK[j*TW+dd];
        areg[m]+=a;
      }
    }
    __syncthreads();
  }
  {
    const size_t aoff = (size_t)blk*(CHK*CHK);
    #pragma unroll
    for (int m=0;m<16;m++) P_ATTN[aoff + t + 256*m] = f2b(areg[m]);
  }

  // Phase 4: qg = QSCALE*q*exp(gc)
  for (int i=t;i<CHK*HD;i+=256){
    int r=i>>7,d=i&127;
    size_t gi = base+(size_t)r*C2+d;
    P_QG[gi] = f2b(QSCALE*b2f(qb[gi])*expn(gc[gi]));
  }
  // Phase 5: w-RHS + k_tail (in-place kb) + egl; solve; w -> qb
  for (int i=t;i<CHK*HD;i+=256){
    int r=i>>7,d=i&127;
    size_t gi = base+(size_t)r*C2+d;
    float kv = b2f(kb[gi]);
    float gv = gc[gi];
    rhs[r][d] = bc[r]*kv*expn(gv);
    kb[gi] = f2b(kv*expn(gl[d]-gv));
  }
  if (t<HD) G_egl[(size_t)blk*HD + t] = expn(gl[t]);
  __syncthreads();
  if (t<HD){
    const int c=t;
    for (int i=1;i<CHK;i++){
      float a=rhs[i][c];
      for (int kk=0;kk<i;kk++) a-=Am[i][kk]*rhs[kk][c];
      rhs[i][c]=a;
    }
  }
  __syncthreads();
  for (int i=t;i<CHK*HD;i+=256){
    int r=i>>7,d=i&127;
    qb[base+(size_t)r*C2+d]=f2b(rhs[r][d]);
  }
}

// ---------------------------------------------------------------------------
// Stage 2: sequential scan over this block's chunks. Grid NHD*8, 256 thr.
// LDS ~58KB. w_=qb, u_=vb, kt_=kb after stage1's in-place writes.
// ---------------------------------------------------------------------------
__global__ void __launch_bounds__(256) stage2_k(int batch, int init)
{
  __shared__ float St[HD][SW+1];
  __shared__ bf16  wq[CHK][HD+8];     // w, then qg
  __shared__ bf16  kt[CHK][HD+8];
  __shared__ bf16  ash[CHK][CHK+8];
  __shared__ float vn[CHK][SW+1];
  __shared__ float egl[HD];

  const bf16* w_  = P_QB;
  const bf16* u_  = P_VB;
  const bf16* kt_ = P_KB;
  const bf16* qg_ = P_QG;

  const int blk = blockIdx.x;
  const int sl  = blk & 7;
  const int h   = blk >> 3;
  const int c0  = sl*SW;
  const int t   = threadIdx.x;
  const int r4  = t>>2, cq = (t&3)*4;
  float* Sg = G_state + ((size_t)(batch*NHD + h))*HD*HD;  // [d][dv]

  for (int i=t;i<HD*SW;i+=256){
    int d=i>>4, c=i&15;
    St[d][c] = init ? 0.f : Sg[(size_t)d*HD + c0 + c];
  }

  for (int ic=0; ic<NCHB; ic++){
    const size_t rbase = (size_t)(ic*CHK)*C2 + h*HD;
    const size_t aoff  = (size_t)(h*NCHB+ic)*(CHK*CHK);
    __syncthreads();
    for (int i=t;i<CHK*HD;i+=256){
      int r=i>>7, d=i&127;
      size_t gi = rbase + (size_t)r*C2 + d;
      wq[r][d] = w_[gi];
      kt[r][d] = kt_[gi];
    }
    for (int i=t;i<CHK*CHK;i+=256) ash[i>>6][i&63] = P_ATTN[aoff+i];
    for (int i=t;i<CHK*SW;i+=256){
      int r=i>>4, c=i&15;
      vn[r][c] = b2f(u_[rbase + (size_t)r*C2 + c0 + c]);
    }
    if (t < HD) egl[t] = G_egl[(size_t)(h*NCHB+ic)*HD + t];
    __syncthreads();
    { // v_new = u - w @ S
      float a0=vn[r4][cq], a1=vn[r4][cq+1], a2=vn[r4][cq+2], a3=vn[r4][cq+3];
      for (int d=0; d<HD; d++){
        float wv = b2f(wq[r4][d]);
        a0 -= wv*St[d][cq]; a1 -= wv*St[d][cq+1]; a2 -= wv*St[d][cq+2]; a3 -= wv*St[d][cq+3];
      }
      vn[r4][cq]=a0; vn[r4][cq+1]=a1; vn[r4][cq+2]=a2; vn[r4][cq+3]=a3;
    }
    __syncthreads();
    // reload wq with qg
    for (int i=t;i<CHK*HD;i+=256){
      int r=i>>7, d=i&127;
      wq[r][d] = qg_[rbase + (size_t)r*C2 + d];
    }
    __syncthreads();
    { // o = attn @ v_new + qg @ S
      float o0=0,o1=0,o2=0,o3=0;
      for (int j=0;j<=r4;j++){
        float av = b2f(ash[r4][j]);
        o0 += av*vn[j][cq]; o1 += av*vn[j][cq+1]; o2 += av*vn[j][cq+2]; o3 += av*vn[j][cq+3];
      }
      for (int d=0;d<HD;d++){
        float qv = b2f(wq[r4][d]);
        o0 += qv*St[d][cq]; o1 += qv*St[d][cq+1]; o2 += qv*St[d][cq+2]; o3 += qv*St[d][cq+3];
      }
      size_t gi = rbase + (size_t)r4*C2 + c0 + cq;
      P_CORE[gi]=f2b(o0); P_CORE[gi+1]=f2b(o1); P_CORE[gi+2]=f2b(o2); P_CORE[gi+3]=f2b(o3);
    }
    { // S = diag(egl) S + k_tail^T @ v_new
      const int d0 = (t>>2)*2, d1 = d0+1;
      float s00=St[d0][cq]*egl[d0], s01=St[d0][cq+1]*egl[d0], s02=St[d0][cq+2]*egl[d0], s03=St[d0][cq+3]*egl[d0];
      float s10=St[d1][cq]*egl[d1], s11=St[d1][cq+1]*egl[d1], s12=St[d1][cq+2]*egl[d1], s13=St[d1][cq+3]*egl[d1];
      for (int j=0;j<CHK;j++){
        float k0v = b2f(kt[j][d0]), k1v = b2f(kt[j][d1]);
        float v0=vn[j][cq], v1=vn[j][cq+1], v2=vn[j][cq+2], v3=vn[j][cq+3];
        s00+=k0v*v0; s01+=k0v*v1; s02+=k0v*v2; s03+=k0v*v3;
        s10+=k1v*v0; s11+=k1v*v1; s12+=k1v*v2; s13+=k1v*v3;
      }
      __syncthreads();   // all old-St reads done before overwrite
      St[d0][cq]=s00; St[d0][cq+1]=s01; St[d0][cq+2]=s02; St[d0][cq+3]=s03;
      St[d1][cq]=s10; St[d1][cq+1]=s11; St[d1][cq+2]=s12; St[d1][cq+3]=s13;
    }
  }
  __syncthreads();
  for (int i=t;i<HD*SW;i+=256){
    int d=i>>4, c=i&15;
    Sg[(size_t)d*HD + c0 + c] = St[d][c];
  }
}

// RMSNorm over D + rms_scale + sigmoid(gate) gating: core,gate -> opre
__global__ void __launch_bounds__(256) rms_gate_k(const float* __restrict__ rms)
{
  __shared__ float part[256];
  __shared__ float scal[16];
  const int t = threadIdx.x;
  const size_t tok = blockIdx.x;
  const int c0 = t*8;
  float v[8];
  const bf16* cr = P_CORE + tok*C2 + c0;
  #pragma unroll
  for (int u=0;u<8;u++) v[u] = b2f(cr[u]);
  float ss=0.f;
  #pragma unroll
  for (int u=0;u<8;u++) ss += v[u]*v[u];
  part[t]=ss; __syncthreads();
  if (t<16){
    float s2=0.f;
    for (int i=0;i<16;i++) s2 += part[t*16+i];
    scal[t] = rsqrtf(s2*(1.f/HD) + 1e-5f);
  }
  __syncthreads();
  float sc = scal[t>>4];
  const bf16* gr = P_GATE + tok*C2 + c0;
  bf16* orow = P_OPRE + tok*C2 + c0;
  #pragma unroll
  for (int u=0;u<8;u++){
    int d = (c0+u)&127;
    float gv = b2f(gr[u]);
    float x = v[u]*sc*rms[d];
    x *= 1.f/(1.f+__expf(-gv));
    orow[u] = f2b(x);
  }
}

// ---------------------------------------------------------------------------
extern "C" void kernel_launch(void* const* d_in, const int* in_sizes, int n_in,
                              void* d_out, int out_size, void* d_ws, size_t ws_size,
                              hipStream_t stream)
{
  const float* x     = (const float*)d_in[0];
  const float* Wq    = (const float*)d_in[1];
  const float* Wk    = (const float*)d_in[2];
  const float* Wv    = (const float*)d_in[3];
  const float* convq = (const float*)d_in[4];
  const float* convk = (const float*)d_in[5];
  const float* convv = (const float*)d_in[6];
  const float* Wb    = (const float*)d_in[7];
  const float* Wfa   = (const float*)d_in[8];
  const float* Wfb   = (const float*)d_in[9];
  const float* Wga   = (const float*)d_in[10];
  const float* Wgb   = (const float*)d_in[11];
  const float* bgb   = (const float*)d_in[12];
  const float* A_log = (const float*)d_in[13];
  const float* dtb   = (const float*)d_in[14];
  const float* rms   = (const float*)d_in[15];
  const float* Wo    = (const float*)d_in[16];
  // d_in[17] = chunk_size (64), fixed.
  (void)d_ws; (void)ws_size;

  dim3 blk2(16,16);
  dim3 gFull(C2/128, TB/128);    // (16,16)
  dim3 gThin(1, TB/128);

  for (int bb=0; bb<NBB; bb++){
    const size_t t0 = (size_t)bb*TB;
    const int batch = (int)(t0 / SEQ);
    const int s0 = (int)(t0 % SEQ);
    const float* xblk = x + t0*C2;

    gemm_k<float,1,0><<<gFull, blk2, 0, stream>>>(xblk, -1, Wq, nullptr, nullptr, 0, TB, C2, C2);
    gemm_k<float,1,0><<<gFull, blk2, 0, stream>>>(xblk, -1, Wk, nullptr, nullptr, 1, TB, C2, C2);
    gemm_k<float,1,0><<<gFull, blk2, 0, stream>>>(xblk, -1, Wv, nullptr, nullptr, 2, TB, C2, C2);
    gemm_k<float,0,1><<<gThin, blk2, 0, stream>>>(xblk, -1, Wb,  nullptr, nullptr, 3, TB, NHD, C2);
    gemm_k<float,0,0><<<gThin, blk2, 0, stream>>>(xblk, -1, Wfa, nullptr, nullptr, 4, TB, HD,  C2);
    gemm_k<float,1,0><<<gThin, blk2, 0, stream>>>(xblk, -1, Wga, nullptr, nullptr, 5, TB, HD,  C2);

    conv_silu_k<<<TB, 256, 0, stream>>>(0, convq, s0, 1);
    conv_silu_k<<<TB, 256, 0, stream>>>(1, convk, s0, 1);
    conv_silu_k<<<TB, 256, 0, stream>>>(2, convv, s0, 0);
    tail_save_k<<<(3*3*C2)/256, 256, 0, stream>>>();

    gemm_k<float,0,0><<<gFull, blk2, 0, stream>>>((const float*)nullptr, 2, Wfb, dtb, nullptr, 6, TB, C2, HD);
    g_transform_k<<<(TB*C2)/256, 256, 0, stream>>>(A_log);
    gcum_k<<<NHD*NCHB, 128, 0, stream>>>();

    stage1_k<<<NHD*NCHB, 256, 0, stream>>>();
    stage2_k<<<NHD*8, 256, 0, stream>>>(batch, s0==0 ? 1 : 0);

    gemm_k<bf16,1,0><<<gFull, blk2, 0, stream>>>((const bf16*)nullptr, 0, Wgb, bgb, nullptr, 7, TB, C2, HD);
    rms_gate_k<<<TB, 256, 0, stream>>>(rms);
    gemm_k<bf16,0,0><<<gFull, blk2, 0, stream>>>((const bf16*)nullptr, 1, Wo, nullptr,
                                                 (float*)d_out + t0*C2, -1, TB, C2, C2);
  }
}

// Round 6
// 5121.394 us; speedup vs baseline: 2.4296x; 2.4296x over previous
//
#include <hip/hip_runtime.h>
#include <hip/hip_bf16.h>

typedef __hip_bfloat16 bf16;
typedef __attribute__((ext_vector_type(4))) float f32x4;
typedef __attribute__((ext_vector_type(8))) short short8;

#define TOK   8192      // B*S
#define SEQ   4096
#define NHD   16        // heads
#define HD    128       // head dim
#define C2    2048      // H*D
#define CHK   64        // chunk size
#define TB    2048      // tokens per stream block PER BATCH
#define TB2   4096      // both batches per iteration
#define NBB   2         // stream iterations
#define NCHB  32        // chunks per half
#define SW    16        // dv slice width in stage2
#define QSCALE 0.08838834764831845f

__device__ __forceinline__ float b2f(bf16 x){ return __bfloat162float(x); }
__device__ __forceinline__ bf16  f2b(float x){ return __float2bfloat16(x); }
__device__ __forceinline__ float expn(float x){ return __expf(fminf(x, 0.f)); }
// row m in [0,TB2) -> global token row (two batch slices)
__device__ __forceinline__ size_t tokrow(int m, int t0a){
  return (size_t)(t0a + m + ((m >= TB) ? (SEQ - TB) : 0));
}

// ---------------------------------------------------------------------------
// Device-global scratch (no d_ws dependence).
// ---------------------------------------------------------------------------
__device__ __attribute__((aligned(16))) unsigned short G_xb  [TB2*C2];
__device__ __attribute__((aligned(16))) unsigned short G_qlin[TB2*C2];
__device__ __attribute__((aligned(16))) unsigned short G_klin[TB2*C2];
__device__ __attribute__((aligned(16))) unsigned short G_vlin[TB2*C2];
__device__ __attribute__((aligned(16))) unsigned short G_qb  [TB2*C2];
__device__ __attribute__((aligned(16))) unsigned short G_kb  [TB2*C2];
__device__ __attribute__((aligned(16))) unsigned short G_vb  [TB2*C2];
__device__ __attribute__((aligned(16))) unsigned short G_qg  [TB2*C2];
__device__ __attribute__((aligned(16))) unsigned short G_gate[TB2*C2];
__device__ __attribute__((aligned(16))) unsigned short G_core[TB2*C2];
__device__ __attribute__((aligned(16))) unsigned short G_opre[TB2*C2];
__device__ __attribute__((aligned(16))) float          G_g   [TB2*C2];
__device__ __attribute__((aligned(16))) unsigned short G_attn[2*NHD*NCHB*CHK*CHK];
__device__ __attribute__((aligned(16))) float          G_egl [2*NHD*NCHB*HD];
__device__ __attribute__((aligned(16))) float          G_beta[TB2*NHD];
__device__ __attribute__((aligned(16))) float          G_fa  [TB2*HD];
__device__ __attribute__((aligned(16))) unsigned short G_ga  [TB2*HD];
__device__ __attribute__((aligned(16))) float          G_state[2*NHD*HD*HD];
__device__ __attribute__((aligned(16))) unsigned short G_qtail[2*3*C2];
__device__ __attribute__((aligned(16))) unsigned short G_ktail[2*3*C2];
__device__ __attribute__((aligned(16))) unsigned short G_vtail[2*3*C2];
// transposed bf16 weights [N][K]
__device__ __attribute__((aligned(16))) unsigned short G_Wqt[C2*C2];
__device__ __attribute__((aligned(16))) unsigned short G_Wkt[C2*C2];
__device__ __attribute__((aligned(16))) unsigned short G_Wvt[C2*C2];
__device__ __attribute__((aligned(16))) unsigned short G_Wot[C2*C2];

#define P_QLIN  ((bf16*)G_qlin)
#define P_KLIN  ((bf16*)G_klin)
#define P_VLIN  ((bf16*)G_vlin)
#define P_QB    ((bf16*)G_qb)
#define P_KB    ((bf16*)G_kb)
#define P_VB    ((bf16*)G_vb)
#define P_QG    ((bf16*)G_qg)
#define P_GATE  ((bf16*)G_gate)
#define P_CORE  ((bf16*)G_core)
#define P_OPRE  ((bf16*)G_opre)
#define P_ATTN  ((bf16*)G_attn)
#define P_QT    ((bf16*)G_qtail)
#define P_KT    ((bf16*)G_ktail)
#define P_VT    ((bf16*)G_vtail)

__device__ __forceinline__ bf16* selWt(int s){
  switch(s){ case 0: return (bf16*)G_Wqt; case 1: return (bf16*)G_Wkt;
             case 2: return (bf16*)G_Wvt; }
  return (bf16*)G_Wot;
}
__device__ __forceinline__ const void* selA_raw(int s){
  switch(s){ case 0: return G_fa; case 1: return G_ga; }
  return nullptr;
}
__device__ __forceinline__ void* selC_raw(int s){
  switch(s){
    case 0: return G_beta; case 1: return G_fa; case 2: return G_ga;
    case 3: return G_g;    case 4: return G_gate;
  }
  return nullptr;
}
__device__ __forceinline__ bf16* selCm(int s){
  switch(s){ case 0: return P_QLIN; case 1: return P_KLIN; }
  return P_VLIN;
}

// ---------------------------------------------------------------------------
// Weight transpose+convert: W f32 [K][N] -> Wt bf16 [N][K].  K=N=2048.
// Grid (32,32), 256 thr, 64x64 tiles.
// ---------------------------------------------------------------------------
__global__ void __launch_bounds__(256) wconv_t_k(const float* __restrict__ W, int outSel)
{
  __shared__ float tile[64][65];
  const int t = threadIdx.x;
  const int n0 = blockIdx.x*64, k0 = blockIdx.y*64;
  const int c4 = (t&15)*4, rr = t>>4;
  #pragma unroll
  for (int i=0;i<4;i++){
    const float* src = W + (size_t)(k0+rr+16*i)*C2 + n0 + c4;
    float4 f = *(const float4*)src;
    tile[rr+16*i][c4+0]=f.x; tile[rr+16*i][c4+1]=f.y;
    tile[rr+16*i][c4+2]=f.z; tile[rr+16*i][c4+3]=f.w;
  }
  __syncthreads();
  bf16* out = selWt(outSel);
  const int nr = t>>3, kc = (t&7)*8;
  #pragma unroll
  for (int p=0;p<2;p++){
    int n = p*32 + nr;
    __attribute__((aligned(16))) bf16 tmp[8];
    #pragma unroll
    for (int j=0;j<8;j++) tmp[j] = f2b(tile[kc+j][n]);
    *(float4*)(out + (size_t)(n0+n)*C2 + k0 + kc) = *(const float4*)tmp;
  }
}

// x block (two slices) f32 -> G_xb bf16 [TB2][C2]. Grid 4096 x 256.
__global__ void __launch_bounds__(256) xconv_k(const float* __restrict__ x, int t0a)
{
  size_t idx = ((size_t)blockIdx.x*256 + threadIdx.x)*8;
  int m = (int)(idx / C2), c = (int)(idx & (C2-1));
  const float* src = x + tokrow(m,t0a)*C2 + c;
  float4 f0 = *(const float4*)src, f1 = *(const float4*)(src+4);
  __attribute__((aligned(16))) bf16 tmp[8];
  tmp[0]=f2b(f0.x); tmp[1]=f2b(f0.y); tmp[2]=f2b(f0.z); tmp[3]=f2b(f0.w);
  tmp[4]=f2b(f1.x); tmp[5]=f2b(f1.y); tmp[6]=f2b(f1.z); tmp[7]=f2b(f1.w);
  *(float4*)((bf16*)G_xb + idx) = *(const float4*)tmp;
}

// ---------------------------------------------------------------------------
// MFMA GEMM: C[M,N] = A[M,K] @ Bt[N,K]^T, bf16 in, f32 acc.
// 128x128 tile, BK=32, 256 thr = 4 waves, each wave 64x64 (4x4 16x16x32 frags).
// aSel: 0=G_xb 1=G_opre.  F32SPLIT: write f32 to Cw with token-split rows,
// else bf16 to selCm(cSel).
// ---------------------------------------------------------------------------
template<int F32SPLIT>
__global__ void __launch_bounds__(256) gemm_mfma(
    int aSel, int bSel, int cSel, float* __restrict__ Cw, int t0a,
    int M, int N, int K)
{
  const bf16* A  = (aSel==0) ? (const bf16*)G_xb : (const bf16*)G_opre;
  const bf16* Bt = selWt(bSel);
  __shared__ bf16 As[128*40];
  __shared__ bf16 Bs[128*40];
  const int t  = threadIdx.x;
  const int l  = t & 63;
  const int wv = t >> 6;
  const int wm = (wv>>1)*64, wn = (wv&1)*64;
  const int bm = blockIdx.y*128, bn = blockIdx.x*128;
  const int lr = l & 15;
  const int lk = (l>>4)*8;
  const int sr = t>>1, sc = (t&1)*16;

  f32x4 acc[4][4];
  #pragma unroll
  for (int i=0;i<4;i++)
    #pragma unroll
    for (int j=0;j<4;j++)
      #pragma unroll
      for (int v=0;v<4;v++) acc[i][j][v] = 0.f;

  for (int k0=0; k0<K; k0+=32){
    const bf16* ga = A  + (size_t)(bm+sr)*K + k0 + sc;
    const bf16* gb = Bt + (size_t)(bn+sr)*K + k0 + sc;
    float4 a0 = *(const float4*)ga; float4 a1 = *(const float4*)(ga+8);
    float4 b0 = *(const float4*)gb; float4 b1 = *(const float4*)(gb+8);
    __syncthreads();
    *(float4*)&As[sr*40+sc]   = a0; *(float4*)&As[sr*40+sc+8] = a1;
    *(float4*)&Bs[sr*40+sc]   = b0; *(float4*)&Bs[sr*40+sc+8] = b1;
    __syncthreads();
    short8 af[4], bfr[4];
    #pragma unroll
    for (int i=0;i<4;i++){
      af[i]  = *(const short8*)&As[(wm+i*16+lr)*40 + lk];
      bfr[i] = *(const short8*)&Bs[(wn+i*16+lr)*40 + lk];
    }
    #pragma unroll
    for (int i=0;i<4;i++)
      #pragma unroll
      for (int j=0;j<4;j++)
        acc[i][j] = __builtin_amdgcn_mfma_f32_16x16x32_bf16(af[i], bfr[j], acc[i][j], 0, 0, 0);
  }

  bf16* Cb = F32SPLIT ? nullptr : selCm(cSel);
  #pragma unroll
  for (int i=0;i<4;i++){
    #pragma unroll
    for (int v=0;v<4;v++){
      int r = bm + wm + i*16 + (l>>4)*4 + v;
      #pragma unroll
      for (int j=0;j<4;j++){
        int col = bn + wn + j*16 + (l&15);
        float val = acc[i][j][v];
        if (F32SPLIT) Cw[tokrow(r,t0a)*C2 + col] = val;
        else          Cb[(size_t)r*C2 + col] = f2b(val);
      }
    }
  }
}

// ---------------------------------------------------------------------------
// VALU GEMM (thin): C[M,N] = A[M,K] @ B[K,N], B f32 (d_in weights).
// ASPLIT: A rows map through tokrow (reading d_in x).
// aSel: -1 -> Ap; 0=G_fa(f32) 1=G_ga(bf16).  cSel per selC_raw.
// ---------------------------------------------------------------------------
template<typename AT, int ASPLIT, int OUT_BF16, int ACT_SIG>
__global__ void __launch_bounds__(256) gemm_k(
    const AT* __restrict__ Ap, int aSel, const float* __restrict__ Bm,
    const float* __restrict__ bias, int cSel, int t0a,
    int M, int N, int K)
{
  const AT* A = (aSel < 0) ? Ap : (const AT*)selA_raw(aSel);
  void* Cv = selC_raw(cSel);

  __shared__ float As[128][17];
  __shared__ float Bs[16][129];
  const int tx = threadIdx.x, ty = threadIdx.y;
  const int tid = ty*16 + tx;
  const int bm = blockIdx.y * 128, bn = blockIdx.x * 128;

  float acc[8][8];
  #pragma unroll
  for (int i=0;i<8;i++)
    #pragma unroll
    for (int j=0;j<8;j++) acc[i][j]=0.f;

  for (int k0=0; k0<K; k0+=16) {
    { int r = tid >> 1, c = (tid & 1)*8;
      size_t rowIdx = ASPLIT ? tokrow(bm+r, t0a) : (size_t)(bm+r);
      const AT* src = A + rowIdx*K + k0 + c;
      if constexpr (sizeof(AT) == 2) {
        float4 f = *(const float4*)src;
        const bf16* e = (const bf16*)&f;
        #pragma unroll
        for (int u=0;u<8;u++) As[r][c+u] = b2f(e[u]);
      } else {
        float4 f0 = *(const float4*)src;
        float4 f1 = *(const float4*)(src+4);
        As[r][c+0]=f0.x; As[r][c+1]=f0.y; As[r][c+2]=f0.z; As[r][c+3]=f0.w;
        As[r][c+4]=f1.x; As[r][c+5]=f1.y; As[r][c+6]=f1.z; As[r][c+7]=f1.w;
      }
    }
    { int r = tid >> 4, c = (tid & 15)*8;
      int gn = bn + c;
      const float* src = Bm + (size_t)(k0+r)*N + gn;
      if (gn + 7 < N) {
        float4 f0 = *(const float4*)src;
        float4 f1 = *(const float4*)(src+4);
        Bs[r][c+0]=f0.x; Bs[r][c+1]=f0.y; Bs[r][c+2]=f0.z; Bs[r][c+3]=f0.w;
        Bs[r][c+4]=f1.x; Bs[r][c+5]=f1.y; Bs[r][c+6]=f1.z; Bs[r][c+7]=f1.w;
      } else {
        #pragma unroll
        for (int u=0;u<8;u++)
          Bs[r][c+u] = (gn+u < N) ? src[u] : 0.f;
      }
    }
    __syncthreads();
    #pragma unroll
    for (int kk=0;kk<16;kk++){
      float a[8], b[8];
      #pragma unroll
      for (int i=0;i<8;i++) a[i] = As[ty + 16*i][kk];
      #pragma unroll
      for (int j=0;j<8;j++) b[j] = Bs[kk][tx + 16*j];
      #pragma unroll
      for (int i=0;i<8;i++)
        #pragma unroll
        for (int j=0;j<8;j++) acc[i][j] += a[i]*b[j];
    }
    __syncthreads();
  }
  #pragma unroll
  for (int i=0;i<8;i++){
    int m = bm + ty + 16*i;
    #pragma unroll
    for (int j=0;j<8;j++){
      int n = bn + tx + 16*j;
      if (n < N) {
        float v = acc[i][j];
        if (bias) v += bias[n];
        if (ACT_SIG) v = 1.f/(1.f + __expf(-v));
        if (OUT_BF16) ((bf16*)Cv)[(size_t)m*N + n] = f2b(v);
        else          ((float*)Cv)[(size_t)m*N + n] = v;
      }
    }
  }
}

// ---------------------------------------------------------------------------
// Causal depthwise conv (K=4) + SiLU + optional per-head l2norm. Grid 2*TB.
// ---------------------------------------------------------------------------
__global__ void __launch_bounds__(256) conv_silu_k(
    int sel, const float* __restrict__ kern, int s0, int do_norm)
{
  const bf16* lin  = sel==0 ? P_QLIN : sel==1 ? P_KLIN : P_VLIN;
  const bf16* tail = sel==0 ? P_QT   : sel==1 ? P_KT   : P_VT;
  bf16*       out  = sel==0 ? P_QB   : sel==1 ? P_KB   : P_VB;

  __shared__ float part[256];
  __shared__ float scal[16];
  const int t = threadIdx.x;
  const int r = blockIdx.x;               // 0..TB2-1
  const int half = r >> 11;               // TB = 2048
  const int rloc = r & (TB-1);
  const int s = s0 + rloc;
  const int c0 = t*8;
  float v[8];
  #pragma unroll
  for (int u=0;u<8;u++) v[u]=0.f;
  for (int j=0;j<4;j++){
    int sp = s - 3 + j;
    if (sp < 0) continue;
    int rl = rloc - 3 + j;
    const bf16* row = (rl >= 0) ? lin + (size_t)(half*TB + rl)*C2 + c0
                                : tail + (size_t)(half*3 + rl+3)*C2 + c0;
    const float* kr = kern + j*C2 + c0;
    #pragma unroll
    for (int u=0;u<8;u++) v[u] += b2f(row[u]) * kr[u];
  }
  #pragma unroll
  for (int u=0;u<8;u++){ float x=v[u]; v[u] = x / (1.f + __expf(-x)); }
  if (do_norm) {
    float ss=0.f;
    #pragma unroll
    for (int u=0;u<8;u++) ss += v[u]*v[u];
    part[t]=ss; __syncthreads();
    if (t<16){
      float s2=0.f;
      for (int i=0;i<16;i++) s2 += part[t*16+i];
      scal[t] = rsqrtf(s2 + 1e-6f);
    }
    __syncthreads();
    float sc = scal[t>>4];
    #pragma unroll
    for (int u=0;u<8;u++) v[u] *= sc;
  }
  bf16* orow = out + (size_t)r*C2 + c0;
  #pragma unroll
  for (int u=0;u<8;u++) orow[u] = f2b(v[u]);
}

// Save last 3 rows of each half of qlin/klin/vlin. Grid 144 x 256.
__global__ void __launch_bounds__(256) tail_save_k()
{
  int i = blockIdx.x*256 + threadIdx.x;   // 2 halves * 3 bufs * 3*C2
  int half = i / (3*3*C2);
  int j = i % (3*3*C2);
  int buf = j / (3*C2), rem = j % (3*C2);
  const bf16* s = (buf==0?P_QLIN:buf==1?P_KLIN:P_VLIN)
                  + (size_t)(half*TB + TB-3)*C2 + rem;
  bf16* d = (buf==0?P_QT:buf==1?P_KT:P_VT) + (size_t)half*3*C2 + rem;
  *d = *s;
}

// g = -exp(A_log[h]) * softplus(g_lin), in-place f32 on G_g (TB2*C2)
__global__ void __launch_bounds__(256) g_transform_k(const float* __restrict__ A_log)
{
  size_t i = (size_t)blockIdx.x*256 + threadIdx.x;
  float x = fminf(G_g[i], 80.f);
  int h = (int)((i >> 7) & (NHD-1));
  float a = __expf(A_log[h]);
  float sp = (x > 20.f) ? x : log1pf(__expf(x));
  G_g[i] = -a * sp;
}

// Per-chunk cumsum of g. Grid 2*NHD*NCHB x 128.
__global__ void __launch_bounds__(128) gcum_k()
{
  const int blk = blockIdx.x;
  const int half = blk >> 9;
  const int rem = blk & 511;
  const int ic = rem % NCHB, h = rem / NCHB;
  const int d = threadIdx.x;
  size_t gi = (size_t)(half*TB + ic*CHK)*C2 + h*HD + d;
  float a = 0.f;
  for (int r=0;r<CHK;r++){ a += G_g[gi]; G_g[gi] = a; gi += C2; }
}

// ---------------------------------------------------------------------------
// Stage 1: per chunk (2*NHD*NCHB = 1024 blocks, 256 thr).
// ---------------------------------------------------------------------------
#define TW 33
__global__ void __launch_bounds__(256) stage1_k()
{
  __shared__ float Am[CHK][CHK+1];
  __shared__ float sh[CHK*(HD+2)];
  __shared__ float bc[CHK];
  __shared__ float gl[HD];

  bf16* qb = P_QB; bf16* kb = P_KB; bf16* vb = P_VB;
  const float* gc = G_g;

  const int blk = blockIdx.x;
  const int half = blk >> 9;
  const int rem = blk & 511;
  const int ic  = rem % NCHB;
  const int h   = rem / NCHB;
  const int t   = threadIdx.x;
  const size_t base = (size_t)(half*TB + ic*CHK)*C2 + h*HD;

  float* tK = sh;
  float* tG = sh + CHK*TW;
  float* tQ = sh + 2*CHK*TW;
  float (*rhs)[HD+2] = (float(*)[HD+2])sh;

  if (t < CHK) bc[t] = G_beta[(size_t)(half*TB + ic*CHK + t)*NHD + h];
  if (t < HD)  gl[t] = gc[base + (size_t)(CHK-1)*C2 + t];
  for (int i=t; i<CHK*(CHK+1); i+=256) ((float*)Am)[i] = 0.f;
  __syncthreads();

  for (int dt=0; dt<4; ++dt){
    const int d0 = dt*32;
    for (int i=t; i<CHK*32; i+=256){
      int r=i>>5, dd=i&31;
      size_t gi = base + (size_t)r*C2 + d0 + dd;
      tK[r*TW+dd] = b2f(kb[gi]);
      tG[r*TW+dd] = gc[gi];
    }
    __syncthreads();
    for (int cell=t; cell<CHK*CHK; cell+=256){
      int i=cell>>6, j=cell&63;
      if (i>j){
        float a=0.f;
        for (int dd=0;dd<32;dd++)
          a += expn(tG[i*TW+dd]-tG[j*TW+dd]) * tK[i*TW+dd]*tK[j*TW+dd];
        Am[i][j] += a;
      }
    }
    __syncthreads();
  }
  for (int cell=t; cell<CHK*CHK; cell+=256){
    int i=cell>>6, j=cell&63;
    Am[i][j] = (i>j) ? Am[i][j]*bc[i] : 0.f;
  }
  __syncthreads();

  for (int i=t;i<CHK*HD;i+=256){
    int r=i>>7, d=i&127;
    rhs[r][d] = bc[r]*b2f(vb[base + (size_t)r*C2 + d]);
  }
  __syncthreads();
  if (t < HD){
    const int c=t;
    for (int i=1;i<CHK;i++){
      float a = rhs[i][c];
      for (int kk=0;kk<i;kk++) a -= Am[i][kk]*rhs[kk][c];
      rhs[i][c]=a;
    }
  }
  __syncthreads();
  for (int i=t;i<CHK*HD;i+=256){
    int r=i>>7,d=i&127;
    vb[base+(size_t)r*C2+d] = f2b(rhs[r][d]);
  }
  __syncthreads();

  float areg[16];
  #pragma unroll
  for (int m=0;m<16;m++) areg[m]=0.f;
  for (int dt=0; dt<4; ++dt){
    const int d0=dt*32;
    for (int i=t;i<CHK*32;i+=256){
      int r=i>>5, dd=i&31;
      size_t gi = base + (size_t)r*C2 + d0+dd;
      tK[r*TW+dd]=b2f(kb[gi]);
      tG[r*TW+dd]=gc[gi];
      tQ[r*TW+dd]=QSCALE*b2f(qb[gi]);
    }
    __syncthreads();
    #pragma unroll
    for (int m=0;m<16;m++){
      int cell=t+256*m, i=cell>>6, j=cell&63;
      if (i>=j){
        float a=0.f;
        for (int dd=0;dd<32;dd++)
          a += expn(tG[i*TW+dd]-tG[j*TW+dd]) * tQ[i*TW+dd]*tK[j*TW+dd];
        areg[m]+=a;
      }
    }
    __syncthreads();
  }
  {
    const size_t aoff = (size_t)blk*(CHK*CHK);
    #pragma unroll
    for (int m=0;m<16;m++) P_ATTN[aoff + t + 256*m] = f2b(areg[m]);
  }

  for (int i=t;i<CHK*HD;i+=256){
    int r=i>>7,d=i&127;
    size_t gi = base+(size_t)r*C2+d;
    P_QG[gi] = f2b(QSCALE*b2f(qb[gi])*expn(gc[gi]));
  }
  for (int i=t;i<CHK*HD;i+=256){
    int r=i>>7,d=i&127;
    size_t gi = base+(size_t)r*C2+d;
    float kv = b2f(kb[gi]);
    float gv = gc[gi];
    rhs[r][d] = bc[r]*kv*expn(gv);
    kb[gi] = f2b(kv*expn(gl[d]-gv));
  }
  if (t<HD) G_egl[(size_t)blk*HD + t] = expn(gl[t]);
  __syncthreads();
  if (t<HD){
    const int c=t;
    for (int i=1;i<CHK;i++){
      float a=rhs[i][c];
      for (int kk=0;kk<i;kk++) a-=Am[i][kk]*rhs[kk][c];
      rhs[i][c]=a;
    }
  }
  __syncthreads();
  for (int i=t;i<CHK*HD;i+=256){
    int r=i>>7,d=i&127;
    qb[base+(size_t)r*C2+d]=f2b(rhs[r][d]);
  }
}

// ---------------------------------------------------------------------------
// Stage 2: scan over chunks. Grid 2*NHD*8 = 256, 256 thr.
// ---------------------------------------------------------------------------
__global__ void __launch_bounds__(256) stage2_k(int init)
{
  __shared__ float St[HD][SW+1];
  __shared__ bf16  wq[CHK][HD+8];
  __shared__ bf16  kt[CHK][HD+8];
  __shared__ bf16  ash[CHK][CHK+8];
  __shared__ float vn[CHK][SW+1];
  __shared__ float egl[HD];

  const bf16* w_  = P_QB;
  const bf16* u_  = P_VB;
  const bf16* kt_ = P_KB;
  const bf16* qg_ = P_QG;

  const int blk = blockIdx.x;
  const int half = blk >> 7;          // == batch
  const int hs  = blk & 127;
  const int sl  = hs & 7;
  const int h   = hs >> 3;
  const int c0  = sl*SW;
  const int t   = threadIdx.x;
  const int r4  = t>>2, cq = (t&3)*4;
  float* Sg = G_state + ((size_t)(half*NHD + h))*HD*HD;

  for (int i=t;i<HD*SW;i+=256){
    int d=i>>4, c=i&15;
    St[d][c] = init ? 0.f : Sg[(size_t)d*HD + c0 + c];
  }

  for (int ic=0; ic<NCHB; ic++){
    const size_t rbase = (size_t)(half*TB + ic*CHK)*C2 + h*HD;
    const size_t aoff  = ((size_t)(half*512 + h*NCHB + ic))*(CHK*CHK);
    __syncthreads();
    for (int i=t;i<CHK*HD;i+=256){
      int r=i>>7, d=i&127;
      size_t gi = rbase + (size_t)r*C2 + d;
      wq[r][d] = w_[gi];
      kt[r][d] = kt_[gi];
    }
    for (int i=t;i<CHK*CHK;i+=256) ash[i>>6][i&63] = P_ATTN[aoff+i];
    for (int i=t;i<CHK*SW;i+=256){
      int r=i>>4, c=i&15;
      vn[r][c] = b2f(u_[rbase + (size_t)r*C2 + c0 + c]);
    }
    if (t < HD) egl[t] = G_egl[((size_t)(half*512 + h*NCHB + ic))*HD + t];
    __syncthreads();
    {
      float a0=vn[r4][cq], a1=vn[r4][cq+1], a2=vn[r4][cq+2], a3=vn[r4][cq+3];
      for (int d=0; d<HD; d++){
        float wv = b2f(wq[r4][d]);
        a0 -= wv*St[d][cq]; a1 -= wv*St[d][cq+1]; a2 -= wv*St[d][cq+2]; a3 -= wv*St[d][cq+3];
      }
      vn[r4][cq]=a0; vn[r4][cq+1]=a1; vn[r4][cq+2]=a2; vn[r4][cq+3]=a3;
    }
    __syncthreads();
    for (int i=t;i<CHK*HD;i+=256){
      int r=i>>7, d=i&127;
      wq[r][d] = qg_[rbase + (size_t)r*C2 + d];
    }
    __syncthreads();
    {
      float o0=0,o1=0,o2=0,o3=0;
      for (int j=0;j<=r4;j++){
        float av = b2f(ash[r4][j]);
        o0 += av*vn[j][cq]; o1 += av*vn[j][cq+1]; o2 += av*vn[j][cq+2]; o3 += av*vn[j][cq+3];
      }
      for (int d=0;d<HD;d++){
        float qv = b2f(wq[r4][d]);
        o0 += qv*St[d][cq]; o1 += qv*St[d][cq+1]; o2 += qv*St[d][cq+2]; o3 += qv*St[d][cq+3];
      }
      size_t gi = rbase + (size_t)r4*C2 + c0 + cq;
      P_CORE[gi]=f2b(o0); P_CORE[gi+1]=f2b(o1); P_CORE[gi+2]=f2b(o2); P_CORE[gi+3]=f2b(o3);
    }
    {
      const int d0 = (t>>2)*2, d1 = d0+1;
      float s00=St[d0][cq]*egl[d0], s01=St[d0][cq+1]*egl[d0], s02=St[d0][cq+2]*egl[d0], s03=St[d0][cq+3]*egl[d0];
      float s10=St[d1][cq]*egl[d1], s11=St[d1][cq+1]*egl[d1], s12=St[d1][cq+2]*egl[d1], s13=St[d1][cq+3]*egl[d1];
      for (int j=0;j<CHK;j++){
        float k0v = b2f(kt[j][d0]), k1v = b2f(kt[j][d1]);
        float v0=vn[j][cq], v1=vn[j][cq+1], v2=vn[j][cq+2], v3=vn[j][cq+3];
        s00+=k0v*v0; s01+=k0v*v1; s02+=k0v*v2; s03+=k0v*v3;
        s10+=k1v*v0; s11+=k1v*v1; s12+=k1v*v2; s13+=k1v*v3;
      }
      __syncthreads();
      St[d0][cq]=s00; St[d0][cq+1]=s01; St[d0][cq+2]=s02; St[d0][cq+3]=s03;
      St[d1][cq]=s10; St[d1][cq+1]=s11; St[d1][cq+2]=s12; St[d1][cq+3]=s13;
    }
  }
  __syncthreads();
  for (int i=t;i<HD*SW;i+=256){
    int d=i>>4, c=i&15;
    Sg[(size_t)d*HD + c0 + c] = St[d][c];
  }
}

// RMSNorm + rms_scale + sigmoid(gate): core,gate -> opre. Grid TB2.
__global__ void __launch_bounds__(256) rms_gate_k(const float* __restrict__ rms)
{
  __shared__ float part[256];
  __shared__ float scal[16];
  const int t = threadIdx.x;
  const size_t tok = blockIdx.x;
  const int c0 = t*8;
  float v[8];
  const bf16* cr = P_CORE + tok*C2 + c0;
  #pragma unroll
  for (int u=0;u<8;u++) v[u] = b2f(cr[u]);
  float ss=0.f;
  #pragma unroll
  for (int u=0;u<8;u++) ss += v[u]*v[u];
  part[t]=ss; __syncthreads();
  if (t<16){
    float s2=0.f;
    for (int i=0;i<16;i++) s2 += part[t*16+i];
    scal[t] = rsqrtf(s2*(1.f/HD) + 1e-5f);
  }
  __syncthreads();
  float sc = scal[t>>4];
  const bf16* gr = P_GATE + tok*C2 + c0;
  bf16* orow = P_OPRE + tok*C2 + c0;
  #pragma unroll
  for (int u=0;u<8;u++){
    int d = (c0+u)&127;
    float gv = b2f(gr[u]);
    float x = v[u]*sc*rms[d];
    x *= 1.f/(1.f+__expf(-gv));
    orow[u] = f2b(x);
  }
}

// ---------------------------------------------------------------------------
extern "C" void kernel_launch(void* const* d_in, const int* in_sizes, int n_in,
                              void* d_out, int out_size, void* d_ws, size_t ws_size,
                              hipStream_t stream)
{
  const float* x     = (const float*)d_in[0];
  const float* Wq    = (const float*)d_in[1];
  const float* Wk    = (const float*)d_in[2];
  const float* Wv    = (const float*)d_in[3];
  const float* convq = (const float*)d_in[4];
  const float* convk = (const float*)d_in[5];
  const float* convv = (const float*)d_in[6];
  const float* Wb    = (const float*)d_in[7];
  const float* Wfa   = (const float*)d_in[8];
  const float* Wfb   = (const float*)d_in[9];
  const float* Wga   = (const float*)d_in[10];
  const float* Wgb   = (const float*)d_in[11];
  const float* bgb   = (const float*)d_in[12];
  const float* A_log = (const float*)d_in[13];
  const float* dtb   = (const float*)d_in[14];
  const float* rms   = (const float*)d_in[15];
  const float* Wo    = (const float*)d_in[16];
  (void)d_ws; (void)ws_size;

  dim3 blk2(16,16);
  dim3 gW(32,32);
  dim3 gM(C2/128, TB2/128);      // (16,32) MFMA grid
  dim3 gThin(1, TB2/128);        // (1,32)

  // one-time per call: weight transpose/convert
  wconv_t_k<<<gW, 256, 0, stream>>>(Wq, 0);
  wconv_t_k<<<gW, 256, 0, stream>>>(Wk, 1);
  wconv_t_k<<<gW, 256, 0, stream>>>(Wv, 2);
  wconv_t_k<<<gW, 256, 0, stream>>>(Wo, 3);

  for (int bb=0; bb<NBB; bb++){
    const int t0a = bb*TB;

    xconv_k<<<TB2*C2/(256*8), 256, 0, stream>>>(x, t0a);

    gemm_mfma<0><<<gM, 256, 0, stream>>>(0, 0, 0, nullptr, t0a, TB2, C2, C2);
    gemm_mfma<0><<<gM, 256, 0, stream>>>(0, 1, 1, nullptr, t0a, TB2, C2, C2);
    gemm_mfma<0><<<gM, 256, 0, stream>>>(0, 2, 2, nullptr, t0a, TB2, C2, C2);

    gemm_k<float,1,0,1><<<gThin, blk2, 0, stream>>>(x, -1, Wb,  nullptr, 0, t0a, TB2, NHD, C2);
    gemm_k<float,1,0,0><<<gThin, blk2, 0, stream>>>(x, -1, Wfa, nullptr, 1, t0a, TB2, HD,  C2);
    gemm_k<float,1,1,0><<<gThin, blk2, 0, stream>>>(x, -1, Wga, nullptr, 2, t0a, TB2, HD,  C2);

    conv_silu_k<<<TB2, 256, 0, stream>>>(0, convq, t0a, 1);
    conv_silu_k<<<TB2, 256, 0, stream>>>(1, convk, t0a, 1);
    conv_silu_k<<<TB2, 256, 0, stream>>>(2, convv, t0a, 0);
    tail_save_k<<<(2*3*3*C2)/256, 256, 0, stream>>>();

    gemm_k<float,0,0,0><<<gM, blk2, 0, stream>>>((const float*)nullptr, 0, Wfb, dtb, 3, 0, TB2, C2, HD);
    g_transform_k<<<(TB2*C2)/256, 256, 0, stream>>>(A_log);
    gcum_k<<<2*NHD*NCHB, 128, 0, stream>>>();

    stage1_k<<<2*NHD*NCHB, 256, 0, stream>>>();
    stage2_k<<<2*NHD*8, 256, 0, stream>>>(bb==0 ? 1 : 0);

    gemm_k<bf16,0,1,0><<<gM, blk2, 0, stream>>>((const bf16*)nullptr, 1, Wgb, bgb, 4, 0, TB2, C2, HD);
    rms_gate_k<<<TB2, 256, 0, stream>>>(rms);

    gemm_mfma<1><<<gM, 256, 0, stream>>>(1, 3, -1, (float*)d_out, t0a, TB2, C2, C2);
  }
}

// Round 7
// 2901.263 us; speedup vs baseline: 4.2888x; 1.7652x over previous
//
#include <hip/hip_runtime.h>
#include <hip/hip_bf16.h>

typedef __hip_bfloat16 bf16;
typedef __attribute__((ext_vector_type(4))) float f32x4;
typedef __attribute__((ext_vector_type(8))) short short8;

#define TOT   8192      // B*S (single pass)
#define SEQ   4096
#define NHD   16
#define HD    128
#define C2    2048
#define CHK   64
#define NCPB  64        // chunks per (batch,head)
#define SW    16        // dv slice width in stage2
#define QSCALE 0.08838834764831845f

__device__ __forceinline__ float b2f(bf16 x){ return __bfloat162float(x); }
__device__ __forceinline__ bf16  f2b(float x){ return __float2bfloat16(x); }
__device__ __forceinline__ float expn(float x){ return __expf(fminf(x, 0.f)); }
__device__ __forceinline__ short bts(float x){
  bf16 b = f2b(x); short s; __builtin_memcpy(&s, &b, 2); return s;
}

// ---------------------------------------------------------------------------
// Device-global scratch
// ---------------------------------------------------------------------------
__device__ __attribute__((aligned(16))) unsigned short G_xb  [TOT*C2];
__device__ __attribute__((aligned(16))) unsigned short G_qlin[TOT*C2];
__device__ __attribute__((aligned(16))) unsigned short G_klin[TOT*C2];
__device__ __attribute__((aligned(16))) unsigned short G_vlin[TOT*C2];
__device__ __attribute__((aligned(16))) unsigned short G_qb  [TOT*C2];
__device__ __attribute__((aligned(16))) unsigned short G_kb  [TOT*C2];
__device__ __attribute__((aligned(16))) unsigned short G_vb  [TOT*C2];
__device__ __attribute__((aligned(16))) unsigned short G_qg  [TOT*C2];
__device__ __attribute__((aligned(16))) unsigned short G_gate[TOT*C2];
__device__ __attribute__((aligned(16))) unsigned short G_core[TOT*C2];
__device__ __attribute__((aligned(16))) unsigned short G_opre[TOT*C2];
__device__ __attribute__((aligned(16))) float          G_g   [TOT*C2];
__device__ __attribute__((aligned(16))) unsigned short G_attn[2048*CHK*CHK];
__device__ __attribute__((aligned(16))) unsigned short G_ktt [2048*CHK*HD];
__device__ __attribute__((aligned(16))) float          G_egl [2048*HD];
__device__ __attribute__((aligned(16))) float          G_beta[TOT*NHD];
__device__ __attribute__((aligned(16))) float          G_fa  [TOT*HD];
__device__ __attribute__((aligned(16))) unsigned short G_ga  [TOT*HD];
__device__ __attribute__((aligned(16))) unsigned short G_Wqt [C2*C2];
__device__ __attribute__((aligned(16))) unsigned short G_Wkt [C2*C2];
__device__ __attribute__((aligned(16))) unsigned short G_Wvt [C2*C2];
__device__ __attribute__((aligned(16))) unsigned short G_Wot [C2*C2];
__device__ __attribute__((aligned(16))) unsigned short G_Wgat[HD*C2];

#define P_QLIN ((bf16*)G_qlin)
#define P_KLIN ((bf16*)G_klin)
#define P_VLIN ((bf16*)G_vlin)
#define P_QB   ((bf16*)G_qb)
#define P_KB   ((bf16*)G_kb)
#define P_VB   ((bf16*)G_vb)
#define P_QG   ((bf16*)G_qg)
#define P_GATE ((bf16*)G_gate)
#define P_CORE ((bf16*)G_core)
#define P_OPRE ((bf16*)G_opre)
#define P_ATTN ((bf16*)G_attn)
#define P_KTT  ((bf16*)G_ktt)

__device__ __forceinline__ const bf16* selWt(int s){
  switch(s){ case 0: return (const bf16*)G_Wqt; case 1: return (const bf16*)G_Wkt;
             case 2: return (const bf16*)G_Wvt; case 3: return (const bf16*)G_Wot; }
  return (const bf16*)G_Wgat;
}
__device__ __forceinline__ bf16* selCm(int s){
  switch(s){ case 0: return P_QLIN; case 1: return P_KLIN;
             case 2: return P_VLIN; }
  return (bf16*)G_ga;
}
__device__ __forceinline__ const void* selA_thin(int s){
  switch(s){ case 0: return G_fa; case 1: return G_ga; }
  return nullptr;
}
__device__ __forceinline__ void* selC_thin(int s){
  switch(s){ case 0: return G_beta; case 1: return G_fa;
             case 2: return G_g; }
  return G_gate;
}

// ---------------------------------------------------------------------------
// Weight transpose+convert: W f32 [K=2048][N] -> Wt bf16 [N][2048].
// Grid (N/64, 32), 256 thr.
// ---------------------------------------------------------------------------
__global__ void __launch_bounds__(256) wconv_t_k(const float* __restrict__ W,
                                                 int outSel, int N)
{
  __shared__ float tile[64][65];
  const int t = threadIdx.x;
  const int n0 = blockIdx.x*64, k0 = blockIdx.y*64;
  const int c4 = (t&15)*4, rr = t>>4;
  #pragma unroll
  for (int i=0;i<4;i++){
    const float* src = W + (size_t)(k0+rr+16*i)*N + n0 + c4;
    float4 f = *(const float4*)src;
    tile[rr+16*i][c4+0]=f.x; tile[rr+16*i][c4+1]=f.y;
    tile[rr+16*i][c4+2]=f.z; tile[rr+16*i][c4+3]=f.w;
  }
  __syncthreads();
  bf16* out = (bf16*)(outSel==0?G_Wqt:outSel==1?G_Wkt:outSel==2?G_Wvt:
                      outSel==3?G_Wot:G_Wgat);
  const int nr = t>>3, kc = (t&7)*8;
  #pragma unroll
  for (int p=0;p<2;p++){
    int n = p*32 + nr;
    __attribute__((aligned(16))) bf16 tmp[8];
    #pragma unroll
    for (int j=0;j<8;j++) tmp[j] = f2b(tile[kc+j][n]);
    *(float4*)(out + (size_t)(n0+n)*C2 + k0 + kc) = *(const float4*)tmp;
  }
}

// x f32 -> G_xb bf16
__global__ void __launch_bounds__(256) xconv_k(const float* __restrict__ x)
{
  size_t idx = ((size_t)blockIdx.x*256 + threadIdx.x)*8;
  const float* src = x + idx;
  float4 f0 = *(const float4*)src, f1 = *(const float4*)(src+4);
  __attribute__((aligned(16))) bf16 tmp[8];
  tmp[0]=f2b(f0.x); tmp[1]=f2b(f0.y); tmp[2]=f2b(f0.z); tmp[3]=f2b(f0.w);
  tmp[4]=f2b(f1.x); tmp[5]=f2b(f1.y); tmp[6]=f2b(f1.z); tmp[7]=f2b(f1.w);
  *(float4*)((bf16*)G_xb + idx) = *(const float4*)tmp;
}

// ---------------------------------------------------------------------------
// MFMA GEMM: C[M,N] = A[M,K=2048] @ Bt[N,K]^T, bf16 in, f32 acc.
// 128x128 tile, BK=32, 4 waves x (64x64).
// outMode 0: bf16 -> selCm(cSel), stride N.  outMode 1: f32 -> Cw, stride N.
// ---------------------------------------------------------------------------
template<int OUTMODE>
__global__ void __launch_bounds__(256) gemm_mfma(
    int aSel, int bSel, int cSel, float* __restrict__ Cw, int N)
{
  const bf16* A  = (aSel==0) ? (const bf16*)G_xb : (const bf16*)G_opre;
  const bf16* Bt = selWt(bSel);
  __shared__ bf16 As[128*40];
  __shared__ bf16 Bs[128*40];
  const int t  = threadIdx.x;
  const int l  = t & 63;
  const int wv = t >> 6;
  const int wm = (wv>>1)*64, wn = (wv&1)*64;
  const int bm = blockIdx.y*128, bn = blockIdx.x*128;
  const int lr = l & 15;
  const int lk = (l>>4)*8;
  const int sr = t>>1, sc = (t&1)*16;

  f32x4 acc[4][4];
  #pragma unroll
  for (int i=0;i<4;i++)
    #pragma unroll
    for (int j=0;j<4;j++)
      #pragma unroll
      for (int v=0;v<4;v++) acc[i][j][v] = 0.f;

  for (int k0=0; k0<C2; k0+=32){
    const bf16* ga = A  + (size_t)(bm+sr)*C2 + k0 + sc;
    const bf16* gb = Bt + (size_t)(bn+sr)*C2 + k0 + sc;
    float4 a0 = *(const float4*)ga; float4 a1 = *(const float4*)(ga+8);
    float4 b0 = *(const float4*)gb; float4 b1 = *(const float4*)(gb+8);
    __syncthreads();
    *(float4*)&As[sr*40+sc]   = a0; *(float4*)&As[sr*40+sc+8] = a1;
    *(float4*)&Bs[sr*40+sc]   = b0; *(float4*)&Bs[sr*40+sc+8] = b1;
    __syncthreads();
    short8 af[4], bfr[4];
    #pragma unroll
    for (int i=0;i<4;i++){
      af[i]  = *(const short8*)&As[(wm+i*16+lr)*40 + lk];
      bfr[i] = *(const short8*)&Bs[(wn+i*16+lr)*40 + lk];
    }
    #pragma unroll
    for (int i=0;i<4;i++)
      #pragma unroll
      for (int j=0;j<4;j++)
        acc[i][j] = __builtin_amdgcn_mfma_f32_16x16x32_bf16(af[i], bfr[j], acc[i][j], 0, 0, 0);
  }

  bf16* Cb = (OUTMODE==0) ? selCm(cSel) : nullptr;
  #pragma unroll
  for (int i=0;i<4;i++){
    #pragma unroll
    for (int v=0;v<4;v++){
      int r = bm + wm + i*16 + (l>>4)*4 + v;
      #pragma unroll
      for (int j=0;j<4;j++){
        int col = bn + wn + j*16 + (l&15);
        float val = acc[i][j][v];
        if (OUTMODE==1) Cw[(size_t)r*N + col] = val;
        else            Cb[(size_t)r*N + col] = f2b(val);
      }
    }
  }
}

// ---------------------------------------------------------------------------
// VALU thin GEMM: C[M,N] = A[M,K] @ B[K,N], B f32 weights.
// ---------------------------------------------------------------------------
template<typename AT, int OUT_BF16, int ACT_SIG>
__global__ void __launch_bounds__(256) gemm_k(
    const AT* __restrict__ Ap, int aSel, const float* __restrict__ Bm,
    const float* __restrict__ bias, int cSel, int M, int N, int K)
{
  const AT* A = (aSel < 0) ? Ap : (const AT*)selA_thin(aSel);
  void* Cv = selC_thin(cSel);

  __shared__ float As[128][17];
  __shared__ float Bs[16][129];
  const int tx = threadIdx.x, ty = threadIdx.y;
  const int tid = ty*16 + tx;
  const int bm = blockIdx.y * 128, bn = blockIdx.x * 128;

  float acc[8][8];
  #pragma unroll
  for (int i=0;i<8;i++)
    #pragma unroll
    for (int j=0;j<8;j++) acc[i][j]=0.f;

  for (int k0=0; k0<K; k0+=16) {
    { int r = tid >> 1, c = (tid & 1)*8;
      const AT* src = A + (size_t)(bm+r)*K + k0 + c;
      if constexpr (sizeof(AT) == 2) {
        float4 f = *(const float4*)src;
        const bf16* e = (const bf16*)&f;
        #pragma unroll
        for (int u=0;u<8;u++) As[r][c+u] = b2f(e[u]);
      } else {
        float4 f0 = *(const float4*)src;
        float4 f1 = *(const float4*)(src+4);
        As[r][c+0]=f0.x; As[r][c+1]=f0.y; As[r][c+2]=f0.z; As[r][c+3]=f0.w;
        As[r][c+4]=f1.x; As[r][c+5]=f1.y; As[r][c+6]=f1.z; As[r][c+7]=f1.w;
      }
    }
    { int r = tid >> 4, c = (tid & 15)*8;
      int gn = bn + c;
      const float* src = Bm + (size_t)(k0+r)*N + gn;
      if (gn + 7 < N) {
        float4 f0 = *(const float4*)src;
        float4 f1 = *(const float4*)(src+4);
        Bs[r][c+0]=f0.x; Bs[r][c+1]=f0.y; Bs[r][c+2]=f0.z; Bs[r][c+3]=f0.w;
        Bs[r][c+4]=f1.x; Bs[r][c+5]=f1.y; Bs[r][c+6]=f1.z; Bs[r][c+7]=f1.w;
      } else {
        #pragma unroll
        for (int u=0;u<8;u++)
          Bs[r][c+u] = (gn+u < N) ? src[u] : 0.f;
      }
    }
    __syncthreads();
    #pragma unroll
    for (int kk=0;kk<16;kk++){
      float a[8], b[8];
      #pragma unroll
      for (int i=0;i<8;i++) a[i] = As[ty + 16*i][kk];
      #pragma unroll
      for (int j=0;j<8;j++) b[j] = Bs[kk][tx + 16*j];
      #pragma unroll
      for (int i=0;i<8;i++)
        #pragma unroll
        for (int j=0;j<8;j++) acc[i][j] += a[i]*b[j];
    }
    __syncthreads();
  }
  #pragma unroll
  for (int i=0;i<8;i++){
    int m = bm + ty + 16*i;
    #pragma unroll
    for (int j=0;j<8;j++){
      int n = bn + tx + 16*j;
      if (n < N) {
        float v = acc[i][j];
        if (bias) v += bias[n];
        if (ACT_SIG) v = 1.f/(1.f + __expf(-v));
        if (OUT_BF16) ((bf16*)Cv)[(size_t)m*N + n] = f2b(v);
        else          ((float*)Cv)[(size_t)m*N + n] = v;
      }
    }
  }
}

// ---------------------------------------------------------------------------
// Causal depthwise conv (K=4) + SiLU + optional l2norm. Grid TOT.
// ---------------------------------------------------------------------------
__global__ void __launch_bounds__(256) conv_silu_k(
    int sel, const float* __restrict__ kern, int do_norm)
{
  const bf16* lin = sel==0 ? P_QLIN : sel==1 ? P_KLIN : P_VLIN;
  bf16*       out = sel==0 ? P_QB   : sel==1 ? P_KB   : P_VB;

  __shared__ float part[256];
  __shared__ float scal[16];
  const int t = threadIdx.x;
  const int r = blockIdx.x;
  const int s = r & (SEQ-1);
  const int c0 = t*8;
  float v[8];
  #pragma unroll
  for (int u=0;u<8;u++) v[u]=0.f;
  for (int j=0;j<4;j++){
    int sp = s - 3 + j;
    if (sp < 0) continue;
    const bf16* row = lin + (size_t)(r-3+j)*C2 + c0;
    const float* kr = kern + j*C2 + c0;
    #pragma unroll
    for (int u=0;u<8;u++) v[u] += b2f(row[u]) * kr[u];
  }
  #pragma unroll
  for (int u=0;u<8;u++){ float x=v[u]; v[u] = x / (1.f + __expf(-x)); }
  if (do_norm) {
    float ss=0.f;
    #pragma unroll
    for (int u=0;u<8;u++) ss += v[u]*v[u];
    part[t]=ss; __syncthreads();
    if (t<16){
      float s2=0.f;
      for (int i=0;i<16;i++) s2 += part[t*16+i];
      scal[t] = rsqrtf(s2 + 1e-6f);
    }
    __syncthreads();
    float sc = scal[t>>4];
    #pragma unroll
    for (int u=0;u<8;u++) v[u] *= sc;
  }
  bf16* orow = out + (size_t)r*C2 + c0;
  #pragma unroll
  for (int u=0;u<8;u++) orow[u] = f2b(v[u]);
}

// g = -exp(A_log[h]) * softplus(g_lin)
__global__ void __launch_bounds__(256) g_transform_k(const float* __restrict__ A_log)
{
  size_t i = (size_t)blockIdx.x*256 + threadIdx.x;
  float x = fminf(G_g[i], 80.f);
  int h = (int)((i >> 7) & (NHD-1));
  float a = __expf(A_log[h]);
  float sp = (x > 20.f) ? x : log1pf(__expf(x));
  G_g[i] = -a * sp;
}

// Per-chunk cumsum. Grid 2048 x 128.
__global__ void __launch_bounds__(128) gcum_k()
{
  const int blk = blockIdx.x;
  const int icg = blk & 127, h = blk >> 7;
  const int d = threadIdx.x;
  size_t gi = (size_t)(icg*CHK)*C2 + h*HD + d;
  float a = 0.f;
  for (int r=0;r<CHK;r++){ a += G_g[gi]; G_g[gi] = a; gi += C2; }
}

// ---------------------------------------------------------------------------
// Stage 1 (fused): grid 2048 (h*128+icg), 256 thr.
// Outputs: u->vb, w->qb, qg, attn, egl, ktt (transposed). kb unchanged.
// ---------------------------------------------------------------------------
#define TW 33
__global__ void __launch_bounds__(256) stage1_k()
{
  __shared__ float Am[CHK][CHK+1];
  __shared__ float sh[CHK*(HD+2)];
  __shared__ float bc[CHK];
  __shared__ float gl[HD];

  const int blk = blockIdx.x;
  const int h   = blk >> 7;
  const int icg = blk & 127;
  const int cid = blk;
  const int t   = threadIdx.x;
  const size_t base = (size_t)(icg*CHK)*C2 + h*HD;

  float* tK = sh;
  float* tG = sh + CHK*TW;
  float* tQ = sh + 2*CHK*TW;
  float (*rhs)[HD+2] = (float(*)[HD+2])sh;

  if (t < CHK) bc[t] = G_beta[(size_t)(icg*CHK + t)*NHD + h];
  if (t < HD)  gl[t] = G_g[base + (size_t)(CHK-1)*C2 + t];
  for (int i=t;i<CHK*(CHK+1);i+=256) ((float*)Am)[i]=0.f;
  __syncthreads();

  float areg[16];
  #pragma unroll
  for (int m=0;m<16;m++) areg[m]=0.f;

  // fused Gram + attn over d-tiles
  for (int dt=0; dt<4; ++dt){
    const int d0 = dt*32;
    for (int i=t;i<CHK*32;i+=256){
      int r=i>>5, dd=i&31;
      size_t gi = base + (size_t)r*C2 + d0 + dd;
      tK[r*TW+dd] = b2f(P_KB[gi]);
      tG[r*TW+dd] = G_g[gi];
      tQ[r*TW+dd] = QSCALE*b2f(P_QB[gi]);
    }
    __syncthreads();
    #pragma unroll
    for (int m=0;m<16;m++){
      int cell=t+256*m, i=cell>>6, j=cell&63;
      if (i>=j){
        float aa=0.f, qq=0.f;
        for (int dd=0;dd<32;dd++){
          float e = expn(tG[i*TW+dd]-tG[j*TW+dd]);
          aa += e * tK[i*TW+dd]*tK[j*TW+dd];
          qq += e * tQ[i*TW+dd]*tK[j*TW+dd];
        }
        if (i>j) Am[i][j] += aa;
        areg[m] += qq;
      }
    }
    __syncthreads();
  }
  {
    const size_t aoff = (size_t)cid*(CHK*CHK);
    #pragma unroll
    for (int m=0;m<16;m++) P_ATTN[aoff + t + 256*m] = f2b(areg[m]);
  }
  for (int cell=t; cell<CHK*CHK; cell+=256){
    int i=cell>>6, j=cell&63;
    if (i>j) Am[i][j] *= bc[i];
  }
  __syncthreads();

  // u-solve
  for (int i=t;i<CHK*HD;i+=256){
    int r=i>>7,d=i&127;
    rhs[r][d] = bc[r]*b2f(P_VB[base+(size_t)r*C2+d]);
  }
  __syncthreads();
  if (t<HD){
    const int c=t;
    for (int i=1;i<CHK;i++){
      float a=rhs[i][c];
      for (int kk=0;kk<i;kk++) a-=Am[i][kk]*rhs[kk][c];
      rhs[i][c]=a;
    }
  }
  __syncthreads();
  for (int i=t;i<CHK*HD;i+=256){
    int r=i>>7,d=i&127;
    P_VB[base+(size_t)r*C2+d]=f2b(rhs[r][d]);
  }
  // qg (qb still original q)
  for (int i=t;i<CHK*HD;i+=256){
    int r=i>>7,d=i&127;
    size_t gi=base+(size_t)r*C2+d;
    P_QG[gi]=f2b(QSCALE*b2f(P_QB[gi])*expn(G_g[gi]));
  }
  if (t<HD) G_egl[(size_t)cid*HD+t]=expn(gl[t]);
  __syncthreads();
  // w-solve
  for (int i=t;i<CHK*HD;i+=256){
    int r=i>>7,d=i&127;
    size_t gi=base+(size_t)r*C2+d;
    rhs[r][d]=bc[r]*b2f(P_KB[gi])*expn(G_g[gi]);
  }
  __syncthreads();
  if (t<HD){
    const int c=t;
    for (int i=1;i<CHK;i++){
      float a=rhs[i][c];
      for (int kk=0;kk<i;kk++) a-=Am[i][kk]*rhs[kk][c];
      rhs[i][c]=a;
    }
  }
  __syncthreads();
  for (int i=t;i<CHK*HD;i+=256){
    int r=i>>7,d=i&127;
    P_QB[base+(size_t)r*C2+d]=f2b(rhs[r][d]);
  }
  // ktt: transpose via Am space (dead)
  bf16* ktb=(bf16*)Am;                 // [HD][65] bf16 = 16640 B, exact fit
  for (int i=t;i<CHK*HD;i+=256){
    int r=i>>7,d=i&127;
    size_t gi=base+(size_t)r*C2+d;
    ktb[d*65+r]=f2b(b2f(P_KB[gi])*expn(gl[d]-G_g[gi]));
  }
  __syncthreads();
  for (int i=t;i<CHK*HD;i+=256){
    P_KTT[(size_t)cid*(CHK*HD) + i]=ktb[(i>>6)*65+(i&63)];
  }
}

// ---------------------------------------------------------------------------
// Stage 2 (MFMA): grid 256 (batch*128 + h*8 + sl), 256 thr = 4 waves.
// Per chunk: T=w@S; vn=u-T; o=ash@vn+qg@S; S=diag(egl)S+kt^T@vn.
// S master f32 in LDS [c][d]; operands bf16.
// ---------------------------------------------------------------------------
__global__ void __launch_bounds__(256) stage2_k()
{
  __shared__ float Sf[SW][HD+4];         // [c][d]
  __shared__ bf16  wqL[CHK][HD+8];       // w, then qg
  __shared__ bf16  ktL[HD][CHK+8];       // [d][j]
  __shared__ bf16  ashL[CHK][CHK+8];
  __shared__ bf16  vnT[SW][CHK+8];       // [c][j]
  __shared__ bf16  uL[CHK][SW+4];        // [j][c]
  __shared__ float egl[HD];

  const int blk = blockIdx.x;
  const int batch = blk >> 7;
  const int h  = (blk >> 3) & 15;
  const int sl = blk & 7;
  const int c0 = sl*SW;
  const int t  = threadIdx.x;
  const int l  = t & 63;
  const int wv = t >> 6;
  const int lane16 = l & 15, quad = l >> 4;
  const int R = wv*16;                   // wave row-tile

  for (int i=t;i<SW*(HD+4);i+=256) ((float*)Sf)[i] = 0.f;

  for (int ic=0; ic<NCPB; ic++){
    const int icg = batch*NCPB + ic;
    const int cid = h*128 + icg;
    const size_t rbase = (size_t)(icg*CHK)*C2 + h*HD;

    // ---- L1: stage chunk data
    float4 qgr[4];
    #pragma unroll
    for (int it=0; it<4; ++it){
      int e = (t + 256*it)*8;
      int r = e >> 7, d = e & 127;
      *(float4*)&wqL[r][d] = *(const float4*)(P_QB + rbase + (size_t)r*C2 + d);
      qgr[it] = *(const float4*)(P_QG + rbase + (size_t)r*C2 + d);
    }
    {
      const bf16* src = P_KTT + (size_t)cid*(CHK*HD);
      #pragma unroll
      for (int it=0; it<4; ++it){
        int e = (t + 256*it)*8;
        int d = e >> 6, r = e & 63;
        *(float4*)&ktL[d][r] = *(const float4*)(src + e);
      }
      const bf16* asrc = P_ATTN + (size_t)cid*(CHK*CHK);
      #pragma unroll
      for (int it=0; it<2; ++it){
        int e = (t + 256*it)*8;
        int i2 = e >> 6, j2 = e & 63;
        *(float4*)&ashL[i2][j2] = *(const float4*)(asrc + e);
      }
      int r = t>>2, c = (t&3)*4;
      const bf16* us = P_VB + rbase + (size_t)r*C2 + c0 + c;
      uL[r][c]=us[0]; uL[r][c+1]=us[1]; uL[r][c+2]=us[2]; uL[r][c+3]=us[3];
      if (t < HD) egl[t] = G_egl[(size_t)cid*HD + t];
    }
    __syncthreads();   // B0

    // ---- C1: T = w @ S ; vn = u - T
    {
      f32x4 acc1;
      #pragma unroll
      for (int v=0;v<4;v++) acc1[v]=0.f;
      #pragma unroll
      for (int ks=0; ks<4; ++ks){
        const int k0 = ks*32;
        short8 af = *(const short8*)&wqL[R+lane16][k0 + quad*8];
        short8 bfr;
        #pragma unroll
        for (int j2=0;j2<8;j2++) bfr[j2] = bts(Sf[lane16][k0 + quad*8 + j2]);
        acc1 = __builtin_amdgcn_mfma_f32_16x16x32_bf16(af, bfr, acc1, 0,0,0);
      }
      #pragma unroll
      for (int v=0;v<4;v++){
        int j = R + quad*4 + v;
        float x = b2f(uL[j][lane16]) - acc1[v];
        vnT[lane16][j] = f2b(x);
      }
    }
    __syncthreads();   // B1: vnT ready; wqL reads done

    // ---- L2: qg into wqL
    #pragma unroll
    for (int it=0; it<4; ++it){
      int e = (t + 256*it)*8;
      int r = e >> 7, d = e & 127;
      *(float4*)&wqL[r][d] = qgr[it];
    }
    __syncthreads();   // B2

    // ---- C2: o = ash@vn + qg@S
    {
      f32x4 acc2;
      #pragma unroll
      for (int v=0;v<4;v++) acc2[v]=0.f;
      #pragma unroll
      for (int ks=0; ks<2; ++ks){
        const int k0 = ks*32;
        short8 af = *(const short8*)&ashL[R+lane16][k0 + quad*8];
        short8 bfr = *(const short8*)&vnT[lane16][k0 + quad*8];
        acc2 = __builtin_amdgcn_mfma_f32_16x16x32_bf16(af, bfr, acc2, 0,0,0);
      }
      #pragma unroll
      for (int ks=0; ks<4; ++ks){
        const int k0 = ks*32;
        short8 af = *(const short8*)&wqL[R+lane16][k0 + quad*8];
        short8 bfr;
        #pragma unroll
        for (int j2=0;j2<8;j2++) bfr[j2] = bts(Sf[lane16][k0 + quad*8 + j2]);
        acc2 = __builtin_amdgcn_mfma_f32_16x16x32_bf16(af, bfr, acc2, 0,0,0);
      }
      #pragma unroll
      for (int v=0;v<4;v++){
        size_t row = (size_t)(icg*CHK) + R + quad*4 + v;
        P_CORE[row*C2 + h*HD + c0 + lane16] = f2b(acc2[v]);
      }
    }
    // ---- C3: S update
    {
      f32x4 accS[2];
      #pragma unroll
      for (int p=0;p<2;p++)
        #pragma unroll
        for (int v=0;v<4;v++) accS[p][v]=0.f;
      #pragma unroll
      for (int p=0;p<2;p++){
        const int dt = wv*2 + p;
        #pragma unroll
        for (int ks=0; ks<2; ++ks){
          const int k0 = ks*32;
          short8 af = *(const short8*)&ktL[dt*16 + lane16][k0 + quad*8];
          short8 bfr = *(const short8*)&vnT[lane16][k0 + quad*8];
          accS[p] = __builtin_amdgcn_mfma_f32_16x16x32_bf16(af, bfr, accS[p], 0,0,0);
        }
      }
      __syncthreads();  // B3: all Sf reads done
      #pragma unroll
      for (int p=0;p<2;p++){
        #pragma unroll
        for (int v=0;v<4;v++){
          int d = (wv*2+p)*16 + quad*4 + v;
          Sf[lane16][d] = Sf[lane16][d]*egl[d] + accS[p][v];
        }
      }
    }
  }
}

// RMSNorm + rms_scale + sigmoid(gate): core,gate -> opre. Grid TOT.
__global__ void __launch_bounds__(256) rms_gate_k(const float* __restrict__ rms)
{
  __shared__ float part[256];
  __shared__ float scal[16];
  const int t = threadIdx.x;
  const size_t tok = blockIdx.x;
  const int c0 = t*8;
  float v[8];
  const bf16* cr = P_CORE + tok*C2 + c0;
  #pragma unroll
  for (int u=0;u<8;u++) v[u] = b2f(cr[u]);
  float ss=0.f;
  #pragma unroll
  for (int u=0;u<8;u++) ss += v[u]*v[u];
  part[t]=ss; __syncthreads();
  if (t<16){
    float s2=0.f;
    for (int i=0;i<16;i++) s2 += part[t*16+i];
    scal[t] = rsqrtf(s2*(1.f/HD) + 1e-5f);
  }
  __syncthreads();
  float sc = scal[t>>4];
  const bf16* gr = P_GATE + tok*C2 + c0;
  bf16* orow = P_OPRE + tok*C2 + c0;
  #pragma unroll
  for (int u=0;u<8;u++){
    int d = (c0+u)&127;
    float gv = b2f(gr[u]);
    float x = v[u]*sc*rms[d];
    x *= 1.f/(1.f+__expf(-gv));
    orow[u] = f2b(x);
  }
}

// ---------------------------------------------------------------------------
extern "C" void kernel_launch(void* const* d_in, const int* in_sizes, int n_in,
                              void* d_out, int out_size, void* d_ws, size_t ws_size,
                              hipStream_t stream)
{
  const float* x     = (const float*)d_in[0];
  const float* Wq    = (const float*)d_in[1];
  const float* Wk    = (const float*)d_in[2];
  const float* Wv    = (const float*)d_in[3];
  const float* convq = (const float*)d_in[4];
  const float* convk = (const float*)d_in[5];
  const float* convv = (const float*)d_in[6];
  const float* Wb    = (const float*)d_in[7];
  const float* Wfa   = (const float*)d_in[8];
  const float* Wfb   = (const float*)d_in[9];
  const float* Wga   = (const float*)d_in[10];
  const float* Wgb   = (const float*)d_in[11];
  const float* bgb   = (const float*)d_in[12];
  const float* A_log = (const float*)d_in[13];
  const float* dtb   = (const float*)d_in[14];
  const float* rms   = (const float*)d_in[15];
  const float* Wo    = (const float*)d_in[16];
  (void)d_ws; (void)ws_size;

  dim3 blk2(16,16);
  dim3 gW(32,32), gWs(2,32);
  dim3 gM(16, TOT/128);          // (16,64)
  dim3 gMn(1, TOT/128);          // N=128
  dim3 gThin(1, TOT/128);

  wconv_t_k<<<gW, 256, 0, stream>>>(Wq, 0, C2);
  wconv_t_k<<<gW, 256, 0, stream>>>(Wk, 1, C2);
  wconv_t_k<<<gW, 256, 0, stream>>>(Wv, 2, C2);
  wconv_t_k<<<gW, 256, 0, stream>>>(Wo, 3, C2);
  wconv_t_k<<<gWs, 256, 0, stream>>>(Wga, 4, HD);

  xconv_k<<<TOT*C2/(256*8), 256, 0, stream>>>(x);

  gemm_mfma<0><<<gM, 256, 0, stream>>>(0, 0, 0, nullptr, C2);
  gemm_mfma<0><<<gM, 256, 0, stream>>>(0, 1, 1, nullptr, C2);
  gemm_mfma<0><<<gM, 256, 0, stream>>>(0, 2, 2, nullptr, C2);
  gemm_mfma<0><<<gMn, 256, 0, stream>>>(0, 4, 3, nullptr, HD);   // ga

  gemm_k<float,0,1><<<gThin, blk2, 0, stream>>>(x, -1, Wb,  nullptr, 0, TOT, NHD, C2);
  gemm_k<float,0,0><<<gThin, blk2, 0, stream>>>(x, -1, Wfa, nullptr, 1, TOT, HD,  C2);

  conv_silu_k<<<TOT, 256, 0, stream>>>(0, convq, 1);
  conv_silu_k<<<TOT, 256, 0, stream>>>(1, convk, 1);
  conv_silu_k<<<TOT, 256, 0, stream>>>(2, convv, 0);

  gemm_k<float,0,0><<<gM, blk2, 0, stream>>>((const float*)nullptr, 0, Wfb, dtb, 2, TOT, C2, HD);
  g_transform_k<<<(TOT*C2)/256, 256, 0, stream>>>(A_log);
  gcum_k<<<2048, 128, 0, stream>>>();

  stage1_k<<<2048, 256, 0, stream>>>();
  stage2_k<<<256, 256, 0, stream>>>();

  gemm_k<bf16,1,0><<<gM, blk2, 0, stream>>>((const bf16*)nullptr, 1, Wgb, bgb, 3, TOT, C2, HD);
  rms_gate_k<<<TOT, 256, 0, stream>>>(rms);

  gemm_mfma<1><<<gM, 256, 0, stream>>>(1, 3, -1, (float*)d_out, C2);
}